// Round 11
// baseline (34.199 us; speedup 1.0000x reference)
//
#include <hip/hip_runtime.h>
#include <hip/hip_bf16.h>
#include <math.h>
#include <stdint.h>

namespace {

typedef __bf16 bf16x8 __attribute__((ext_vector_type(8)));
typedef float f32x4 __attribute__((ext_vector_type(4)));

constexpr int L = 64;
constexpr int DH = 64;

// Swizzle key: distinct across BOTH stride-1 and stride-4 row sequences.
__device__ __forceinline__ int kkey(int r) { return (r ^ (r >> 2)) & 7; }
// bf16 C tile: byte offset of (row,col), 128B rows, 16B-slot XOR swizzle.
__device__ __forceinline__ int swzb(int row, int col) {
  return row * 128 + ((((col >> 3) ^ kkey(row)) & 7) << 4) + (col & 7) * 2;
}

__device__ __forceinline__ unsigned short bfbits(float f) {
  __bf16 h = (__bf16)f;
  return __builtin_bit_cast(unsigned short, h);
}
__device__ __forceinline__ __bf16 tobf(float f) { return (__bf16)f; }
__device__ __forceinline__ unsigned long long pack4(float a, float b, float c,
                                                    float d) {
  return (unsigned long long)bfbits(a) | ((unsigned long long)bfbits(b) << 16) |
         ((unsigned long long)bfbits(c) << 32) |
         ((unsigned long long)bfbits(d) << 48);
}

// Direct global->LDS DMA, 16B per lane (LDS dest = uniform base + lane*16).
__device__ __forceinline__ void gload16(const float* gsrc, float* ldst) {
  __builtin_amdgcn_global_load_lds(
      (const __attribute__((address_space(1))) uint32_t*)gsrc,
      (__attribute__((address_space(3))) uint32_t*)ldst, 16, 0, 0);
}

// One wave = one chunk. ALL of Q,K,V staged fp32 via global_load_lds with
// source 16B-slot pre-swizzle (LDS linear, m173/m104). No dest-VGPR input
// loads left except the 2 gate scalars -> nothing for the compiler's
// load-sinking to serialize; one vmcnt(0) drain for 48 pipelined DMAs.
// V^T fragments extracted straight from the fp32 V tile (64 ds_read_b32,
// swizzle-spread banks) -- the reg->scatter pass is deleted entirely.
__global__ __launch_bounds__(64, 1) void mlstm_mfma(
    const float* __restrict__ q, const float* __restrict__ k,
    const float* __restrict__ v, const float* __restrict__ ig,
    const float* __restrict__ fg, float* __restrict__ out) {

  __shared__ __align__(16) float q_lds[64 * 64];  // fp32, slot-swizzled; low 8KB reused for C (bf16)
  __shared__ __align__(16) float k_lds[64 * 64];  // fp32, slot-swizzled
  __shared__ __align__(16) float v_lds[64 * 64];  // fp32 [j][d], slot-swizzled

  const int lane = threadIdx.x;
  const int m = lane & 15;   // fragment row/col index
  const int g = lane >> 4;   // fragment k-group
  const size_t cbase = (size_t)blockIdx.x * (L * DH);
  const size_t gb = (size_t)blockIdx.x * L;

  // ======== phase 0: gate loads, then 48 DMA loads (all pipelined) ========
  const float fgv = fg[gb + lane];
  const float igv = ig[gb + lane];

  {
    const int rsub = lane >> 4;
    const int slot = lane & 15;
#pragma unroll
    for (int it = 0; it < 16; ++it) {
      const int r = it * 4 + rsub;
      const int coff = r * 64 + ((slot ^ kkey(r)) << 2);
      gload16(q + cbase + coff, &q_lds[it * 256]);
      gload16(k + cbase + coff, &k_lds[it * 256]);
      gload16(v + cbase + coff, &v_lds[it * 256]);  // row j = r, col d
    }
  }

  // ======== gate scan in the DMA shadow (VALU + 2 early loads only) =======
  float ea, eb, em;  // lane l holds values for time index l
  {
    const float lf = fminf(fgv, 0.f) - log1pf(__expf(-fabsf(fgv)));
    float cum = lf;
#pragma unroll
    for (int o = 1; o < 64; o <<= 1) {
      const float t = __shfl_up(cum, o, 64);
      if (lane >= o) cum += t;
    }
    const float a = igv - cum;
    float b = a;
#pragma unroll
    for (int o = 1; o < 64; o <<= 1) {
      const float t = __shfl_up(b, o, 64);
      if (lane >= o) b = fmaxf(b, t);
    }
    const float bmax = __shfl(b, 63, 64);
    ea = 0.125f * __expf(a - bmax);  // fold 1/sqrt(DH)
    eb = __expf(bmax - b);
    em = __expf(-(b + cum));
  }

  // ======== single drain: all DMA complete ================================
  asm volatile("s_waitcnt vmcnt(0)" ::: "memory");

  // ======== Q/K fragments from fp32 LDS (b128 pairs, ~2-way) + cvt ========
  bf16x8 qf[4][2], kf[4][2];
#pragma unroll
  for (int rb = 0; rb < 4; ++rb)
#pragma unroll
    for (int kb = 0; kb < 2; ++kb) {
      const int row = rb * 16 + m;
      const int c4 = kb * 8 + g * 2;
      const int o0 = row * 64 + (((c4 + 0) ^ kkey(row)) << 2);
      const int o1 = row * 64 + (((c4 + 1) ^ kkey(row)) << 2);
      const f32x4 ka = *(const f32x4*)&k_lds[o0];
      const f32x4 kb4 = *(const f32x4*)&k_lds[o1];
      const f32x4 qa = *(const f32x4*)&q_lds[o0];
      const f32x4 qb = *(const f32x4*)&q_lds[o1];
      kf[rb][kb] = bf16x8{tobf(ka[0]), tobf(ka[1]), tobf(ka[2]), tobf(ka[3]),
                          tobf(kb4[0]), tobf(kb4[1]), tobf(kb4[2]), tobf(kb4[3])};
      qf[rb][kb] = bf16x8{tobf(qa[0]), tobf(qa[1]), tobf(qa[2]), tobf(qa[3]),
                          tobf(qb[0]), tobf(qb[1]), tobf(qb[2]), tobf(qb[3])};
    }

  // ======== V^T fragments: strided scalar reads from fp32 V tile ==========
  // vfr[db][jb][t] = V[j = jb*32+g*8+t][d = db*16+m]
  bf16x8 vfr[4][2];
  {
    const int d4 = 0;  // silence unused warnings pattern (computed below)
    (void)d4;
#pragma unroll
    for (int db = 0; db < 4; ++db) {
      const int d = db * 16 + m;
      const int dslot = d >> 2;   // 16B slot of column d
      const int dsub = d & 3;
#pragma unroll
      for (int jb = 0; jb < 2; ++jb) {
        float tv[8];
#pragma unroll
        for (int t = 0; t < 8; ++t) {
          const int j = jb * 32 + g * 8 + t;
          tv[t] = v_lds[j * 64 + ((dslot ^ kkey(j)) << 2) + dsub];
        }
        vfr[db][jb] = bf16x8{tobf(tv[0]), tobf(tv[1]), tobf(tv[2]), tobf(tv[3]),
                             tobf(tv[4]), tobf(tv[5]), tobf(tv[6]), tobf(tv[7])};
      }
    }
  }

  // ======== mm1: S^T tiles (only rb <= cb are causal) =====================
  f32x4 st[4][4];
#pragma unroll
  for (int cb = 0; cb < 4; ++cb)
#pragma unroll
    for (int rb = 0; rb < 4; ++rb) {
      if (rb > cb) continue;
      f32x4 acc = {0.f, 0.f, 0.f, 0.f};
      acc = __builtin_amdgcn_mfma_f32_16x16x32_bf16(kf[rb][0], qf[cb][0], acc, 0, 0, 0);
      acc = __builtin_amdgcn_mfma_f32_16x16x32_bf16(kf[rb][1], qf[cb][1], acc, 0, 0, 0);
      st[rb][cb] = acc;
    }

  // ======== gating, row-sum, normalizer; write C over q_lds ===============
  char* cs_raw = (char*)q_lds;  // Q frags consumed; same-array WAR order
  float ea_j[4][4];
#pragma unroll
  for (int rb = 0; rb < 4; ++rb)
#pragma unroll
    for (int e = 0; e < 4; ++e)
      ea_j[rb][e] = __shfl(ea, rb * 16 + g * 4 + e, 64);

  float invr[4];
#pragma unroll
  for (int cb = 0; cb < 4; ++cb) {
    const int i = cb * 16 + m;
    const float ebv = __shfl(eb, i, 64);
    const float emv = __shfl(em, i, 64);
    float rs = 0.f;
    const int rbfill = cb | 1;  // zero-fill the jb ranges mm2 will read
#pragma unroll
    for (int rb = 0; rb < 4; ++rb) {
      if (rb > rbfill) continue;
      unsigned long long wp = 0ull;
      if (rb <= cb) {
        float vv[4];
#pragma unroll
        for (int e = 0; e < 4; ++e) {
          const int j = rb * 16 + g * 4 + e;
          vv[e] = (j <= i) ? st[rb][cb][e] * ea_j[rb][e] * ebv : 0.f;
          rs += vv[e];
        }
        wp = pack4(vv[0], vv[1], vv[2], vv[3]);
      }
      *(unsigned long long*)(cs_raw + swzb(i, rb * 16 + g * 4)) = wp;
    }
    rs += __shfl_xor(rs, 16, 64);
    rs += __shfl_xor(rs, 32, 64);
    const float n = fmaxf(fabsf(rs), emv);
    invr[cb] = 1.f / (n + 1e-6f);
  }

  // ======== mm2 (per-ib): H^T = V^T * C^T, scale + store ===================
#pragma unroll
  for (int ib = 0; ib < 4; ++ib) {
    const int i = ib * 16 + m;
    const bf16x8 c0 = *(const bf16x8*)(cs_raw + swzb(i, g * 8));
    f32x4 acc[4];
#pragma unroll
    for (int db = 0; db < 4; ++db) {
      f32x4 z = {0.f, 0.f, 0.f, 0.f};
      acc[db] = __builtin_amdgcn_mfma_f32_16x16x32_bf16(vfr[db][0], c0, z, 0, 0, 0);
    }
    if (ib >= 2) {
      const bf16x8 c1 = *(const bf16x8*)(cs_raw + swzb(i, 32 + g * 8));
#pragma unroll
      for (int db = 0; db < 4; ++db)
        acc[db] = __builtin_amdgcn_mfma_f32_16x16x32_bf16(vfr[db][1], c1, acc[db], 0, 0, 0);
    }
    const float iv = invr[ib];
    float* op = out + cbase + i * 64 + g * 4;
#pragma unroll
    for (int db = 0; db < 4; ++db) {
      const f32x4 hv = acc[db];
      *(float4*)(op + db * 16) =
          make_float4(hv[0] * iv, hv[1] * iv, hv[2] * iv, hv[3] * iv);
    }
  }
}

}  // namespace

extern "C" void kernel_launch(void* const* d_in, const int* in_sizes, int n_in,
                              void* d_out, int out_size, void* d_ws,
                              size_t ws_size, hipStream_t stream) {
  const float* q = (const float*)d_in[0];
  const float* k = (const float*)d_in[1];
  const float* v = (const float*)d_in[2];
  const float* ig = (const float*)d_in[3];
  const float* fg = (const float*)d_in[4];
  float* out = (float*)d_out;

  const int total = in_sizes[0];         // B*NH*S*DH
  const int nchunks = total / (L * DH);  // 2048
  mlstm_mfma<<<dim3(nchunks), dim3(64), 0, stream>>>(q, k, v, ig, fg, out);
}

// Round 12
// 27.911 us; speedup vs baseline: 1.2253x; 1.2253x over previous
//
#include <hip/hip_runtime.h>
#include <hip/hip_bf16.h>
#include <math.h>
#include <stdint.h>

namespace {

typedef __bf16 bf16x8 __attribute__((ext_vector_type(8)));
typedef float f32x4 __attribute__((ext_vector_type(4)));

constexpr int L = 64;
constexpr int DH = 64;

// Swizzle key: distinct across BOTH stride-1 and stride-4 row sequences.
__device__ __forceinline__ int kkey(int r) { return (r ^ (r >> 2)) & 7; }
// Per-wave C tile: 16 rows x 64 cols bf16, 128B rows, 16B-slot XOR swizzle.
__device__ __forceinline__ int swzC(int r, int col) {
  return r * 128 + ((((col >> 3) ^ kkey(r)) & 7) << 4) + (col & 7) * 2;
}

__device__ __forceinline__ unsigned short bfbits(float f) {
  __bf16 h = (__bf16)f;
  return __builtin_bit_cast(unsigned short, h);
}
__device__ __forceinline__ __bf16 tobf(float f) { return (__bf16)f; }
__device__ __forceinline__ unsigned long long pack4(float a, float b, float c,
                                                    float d) {
  return (unsigned long long)bfbits(a) | ((unsigned long long)bfbits(b) << 16) |
         ((unsigned long long)bfbits(c) << 32) |
         ((unsigned long long)bfbits(d) << 48);
}

// Direct global->LDS DMA, 16B per lane (LDS dest = uniform base + lane*16).
__device__ __forceinline__ void gload16(const float* gsrc, float* ldst) {
  __builtin_amdgcn_global_load_lds(
      (const __attribute__((address_space(1))) uint32_t*)gsrc,
      (__attribute__((address_space(3))) uint32_t*)ldst, 16, 0, 0);
}

// 4 waves per chunk SHARING DMA-staged K/V LDS tiles. Wave w owns output
// rows [16w,16w+16). Symmetric preludes (each wave: 8 DMA issues + its own
// 4 Q fragment loads + redundant gate scan) -> one low-skew barrier.
// LDS = 16K(K) + 16K(V) + 8K(C) = 40KB -> 4 blocks/CU = 16 waves/CU,
// with the R10/R11-proven pipelined-DMA load path (no dest-VGPR sinking).
__global__ __launch_bounds__(256, 4) void mlstm_mfma(
    const float* __restrict__ q, const float* __restrict__ k,
    const float* __restrict__ v, const float* __restrict__ ig,
    const float* __restrict__ fg, float* __restrict__ out) {

  __shared__ __align__(16) float k_lds[64 * 64];   // fp32, slot-swizzled
  __shared__ __align__(16) float v_lds[64 * 64];   // fp32 [j][d], swizzled
  __shared__ __align__(16) char cs_raw[4][16 * 128];  // per-wave C bf16

  const int tid = threadIdx.x;
  const int w = tid >> 6;    // wave id = output row-block
  const int lane = tid & 63;
  const int m = lane & 15;
  const int g = lane >> 4;
  const size_t cbase = (size_t)blockIdx.x * (L * DH);
  const size_t gb = (size_t)blockIdx.x * L;

  // ======== gate loads first =============================================
  const float fgv = fg[gb + lane];
  const float igv = ig[gb + lane];

  // ======== K,V -> LDS DMA (8 instrs per wave, source pre-swizzled) ======
  {
    const int rsub = lane >> 4;
    const int slot = lane & 15;
#pragma unroll
    for (int s = 0; s < 4; ++s) {
      const int it = w * 4 + s;          // LDS segment; rows it*4..it*4+3
      const int r = it * 4 + rsub;
      const int coff = r * 64 + ((slot ^ kkey(r)) << 2);
      gload16(k + cbase + coff, &k_lds[it * 256]);
      gload16(v + cbase + coff, &v_lds[it * 256]);
    }
  }

  // ======== Q fragments: direct reg loads, own rows only (4 float4) ======
  float4 qbuf[2][2];
#pragma unroll
  for (int kb = 0; kb < 2; ++kb) {
    const int off = (w * 16 + m) * 64 + kb * 32 + g * 8;
    qbuf[kb][0] = *(const float4*)(q + cbase + off);
    qbuf[kb][1] = *(const float4*)(q + cbase + off + 4);
  }

  // ======== per-wave gate scan (redundant; removes coupling) =============
  float ea, eb, em;  // lane l holds values for time index l
  {
    const float lf = fminf(fgv, 0.f) - log1pf(__expf(-fabsf(fgv)));
    float cum = lf;
#pragma unroll
    for (int o = 1; o < 64; o <<= 1) {
      const float t = __shfl_up(cum, o, 64);
      if (lane >= o) cum += t;
    }
    const float a = igv - cum;
    float b = a;
#pragma unroll
    for (int o = 1; o < 64; o <<= 1) {
      const float t = __shfl_up(b, o, 64);
      if (lane >= o) b = fmaxf(b, t);
    }
    const float bmax = __shfl(b, 63, 64);
    ea = 0.125f * __expf(a - bmax);  // fold 1/sqrt(DH)
    eb = __expf(bmax - b);
    em = __expf(-(b + cum));
  }

  // ======== cvt Q fragments ==============================================
  bf16x8 qf[2];
#pragma unroll
  for (int kb = 0; kb < 2; ++kb) {
    const float4 q0 = qbuf[kb][0], q1 = qbuf[kb][1];
    qf[kb] = bf16x8{tobf(q0.x), tobf(q0.y), tobf(q0.z), tobf(q0.w),
                    tobf(q1.x), tobf(q1.y), tobf(q1.z), tobf(q1.w)};
  }

  // ======== drain DMA + barrier (symmetric arrival) ======================
  asm volatile("s_waitcnt vmcnt(0)" ::: "memory");
  __syncthreads();

  // ======== K fragments from shared LDS (rb <= w only) ===================
  bf16x8 kf[4][2];
#pragma unroll
  for (int rb = 0; rb < 4; ++rb) {
    if (rb <= w) {  // wave-uniform
#pragma unroll
      for (int kb = 0; kb < 2; ++kb) {
        const int row = rb * 16 + m;
        const int c4 = kb * 8 + g * 2;
        const int o0 = row * 64 + (((c4 + 0) ^ kkey(row)) << 2);
        const int o1 = row * 64 + (((c4 + 1) ^ kkey(row)) << 2);
        const f32x4 ka = *(const f32x4*)&k_lds[o0];
        const f32x4 kb4 = *(const f32x4*)&k_lds[o1];
        kf[rb][kb] =
            bf16x8{tobf(ka[0]), tobf(ka[1]), tobf(ka[2]), tobf(ka[3]),
                   tobf(kb4[0]), tobf(kb4[1]), tobf(kb4[2]), tobf(kb4[3])};
      }
    }
  }

  // ======== V^T fragments: strided scalar reads (jb < njb) ===============
  const int njb = (w >= 2) ? 2 : 1;
  bf16x8 vfr[4][2];
#pragma unroll
  for (int db = 0; db < 4; ++db) {
    const int d = db * 16 + m;
    const int dslot = d >> 2;
    const int dsub = d & 3;
#pragma unroll
    for (int jb = 0; jb < 2; ++jb) {
      if (jb < njb) {
        float tv[8];
#pragma unroll
        for (int t = 0; t < 8; ++t) {
          const int j = jb * 32 + g * 8 + t;
          tv[t] = v_lds[j * 64 + ((dslot ^ kkey(j)) << 2) + dsub];
        }
        vfr[db][jb] =
            bf16x8{tobf(tv[0]), tobf(tv[1]), tobf(tv[2]), tobf(tv[3]),
                   tobf(tv[4]), tobf(tv[5]), tobf(tv[6]), tobf(tv[7])};
      }
    }
  }

  // ======== mm1: S^T tiles for cb = w, rb <= w ===========================
  f32x4 st[4];
#pragma unroll
  for (int rb = 0; rb < 4; ++rb) {
    if (rb <= w) {
      f32x4 acc = {0.f, 0.f, 0.f, 0.f};
      acc = __builtin_amdgcn_mfma_f32_16x16x32_bf16(kf[rb][0], qf[0], acc, 0, 0, 0);
      acc = __builtin_amdgcn_mfma_f32_16x16x32_bf16(kf[rb][1], qf[1], acc, 0, 0, 0);
      st[rb] = acc;
    }
  }

  // ======== gating, C write (own tile), stabilized normalizer ============
  char* cw = cs_raw[w];
  const int i = w * 16 + m;
  const float ebv = __shfl(eb, i, 64);
  const float emv = __shfl(em, i, 64);
  float ea_j[4][4];
#pragma unroll
  for (int rb = 0; rb < 4; ++rb)
#pragma unroll
    for (int e = 0; e < 4; ++e)
      ea_j[rb][e] = __shfl(ea, rb * 16 + g * 4 + e, 64);

  float rs = 0.f;
  const int rbfill = w | 1;  // zero-fill the jb ranges mm2 will read
#pragma unroll
  for (int rb = 0; rb < 4; ++rb) {
    if (rb > rbfill) continue;
    unsigned long long wp = 0ull;
    if (rb <= w) {
      float vv[4];
#pragma unroll
      for (int e = 0; e < 4; ++e) {
        const int j = rb * 16 + g * 4 + e;
        vv[e] = (j <= i) ? st[rb][e] * ea_j[rb][e] * ebv : 0.f;
        rs += vv[e];
      }
      wp = pack4(vv[0], vv[1], vv[2], vv[3]);
    }
    *(unsigned long long*)(cw + swzC(m, rb * 16 + g * 4)) = wp;
  }
  rs += __shfl_xor(rs, 16, 64);
  rs += __shfl_xor(rs, 32, 64);
  const float invv = 1.f / (fmaxf(fabsf(rs), emv) + 1e-6f);

  // ======== mm2: H^T block for own rows ==================================
  const bf16x8 c0 = *(const bf16x8*)(cw + swzC(m, g * 8));
  f32x4 acc[4];
#pragma unroll
  for (int db = 0; db < 4; ++db) {
    f32x4 z = {0.f, 0.f, 0.f, 0.f};
    acc[db] = __builtin_amdgcn_mfma_f32_16x16x32_bf16(vfr[db][0], c0, z, 0, 0, 0);
  }
  if (w >= 2) {
    const bf16x8 c1 = *(const bf16x8*)(cw + swzC(m, 32 + g * 8));
#pragma unroll
    for (int db = 0; db < 4; ++db)
      acc[db] = __builtin_amdgcn_mfma_f32_16x16x32_bf16(vfr[db][1], c1, acc[db], 0, 0, 0);
  }

  // ======== normalize + store ============================================
  float* op = out + cbase + i * 64 + g * 4;
#pragma unroll
  for (int db = 0; db < 4; ++db) {
    const f32x4 hv = acc[db];
    *(float4*)(op + db * 16) =
        make_float4(hv[0] * invv, hv[1] * invv, hv[2] * invv, hv[3] * invv);
  }
}

}  // namespace

extern "C" void kernel_launch(void* const* d_in, const int* in_sizes, int n_in,
                              void* d_out, int out_size, void* d_ws,
                              size_t ws_size, hipStream_t stream) {
  const float* q = (const float*)d_in[0];
  const float* k = (const float*)d_in[1];
  const float* v = (const float*)d_in[2];
  const float* ig = (const float*)d_in[3];
  const float* fg = (const float*)d_in[4];
  float* out = (float*)d_out;

  const int total = in_sizes[0];         // B*NH*S*DH
  const int nchunks = total / (L * DH);  // 2048
  mlstm_mfma<<<dim3(nchunks), dim3(256), 0, stream>>>(q, k, v, ig, fg, out);
}